// Round 1
// baseline (384.740 us; speedup 1.0000x reference)
//
#include <hip/hip_runtime.h>
#include <type_traits>

#define N_TOK 65536
#define K_CODE 8192
#define D_DIM 64

constexpr float DECAY = 0.9f;
constexpr float OMD = 0.1f;   // 1 - DECAY
constexpr float EPS = 1e-5f;

// ---- output layout (floats), per reference return order ----
constexpr int OUT_QE = 0;
constexpr int OUT_W  = 1;
constexpr int OUT_CS = 1 + K_CODE * D_DIM;
constexpr int OUT_EA = OUT_CS + K_CODE;

// ---- workspace layout (floats) ----
constexpr int WS_QE     = 0;
constexpr int WS_NSUM   = 1;                            // 8 partial slots [1..8]
constexpr int WS_COUNTS = 16;
constexpr int WS_EMBSUM = WS_COUNTS + K_CODE;
constexpr int WS_WHI    = WS_EMBSUM + K_CODE * D_DIM;   // ushort[K*64] bf16 hi, XOR-swizzled
constexpr int WS_WLO    = WS_WHI + K_CODE * D_DIM / 2;  // ushort[K*64] bf16 lo, XOR-swizzled
constexpr int WS_CNP    = WS_WLO + K_CODE * D_DIM / 2;  // uint[K]: bf16(cn+64) hi | lo<<16
constexpr int WS_ZERO   = WS_WHI;                       // floats to memset

typedef __attribute__((ext_vector_type(16))) float floatx16;
typedef __attribute__((ext_vector_type(8)))  short short8;
typedef __attribute__((ext_vector_type(8)))  __bf16 bf16x8;

// SFINAE hedge: mfma bf16 builtin takes v8bf16 on newer clang, v8i16 on older.
template <typename T, typename = void> struct mfma_takes : std::false_type {};
template <typename T>
struct mfma_takes<T, std::void_t<decltype(__builtin_amdgcn_mfma_f32_32x32x16_bf16(
    std::declval<T>(), std::declval<T>(), std::declval<floatx16>(), 0, 0, 0))>>
    : std::true_type {};

__device__ __forceinline__ floatx16 MFMA(short8 a, short8 b, floatx16 c) {
  if constexpr (mfma_takes<bf16x8>::value) {
    return __builtin_amdgcn_mfma_f32_32x32x16_bf16(
        __builtin_bit_cast(bf16x8, a), __builtin_bit_cast(bf16x8, b), c, 0, 0, 0);
  } else {
    return __builtin_amdgcn_mfma_f32_32x32x16_bf16(a, b, c, 0, 0, 0);
  }
}

__device__ __forceinline__ unsigned short bf16rne(float x) {
  unsigned int u = __float_as_uint(x);
  return (unsigned short)((u + 0x7FFFu + ((u >> 16) & 1u)) >> 16);
}

// async global->LDS 16B DMA (HW writes LDS at wave-uniform dst + lane*16)
__device__ __forceinline__ void gload_lds16(const unsigned short* g, unsigned short* l) {
#if defined(__has_builtin) && __has_builtin(__builtin_amdgcn_global_load_lds)
  typedef __attribute__((address_space(1))) void gvoid;
  typedef __attribute__((address_space(3))) void lvoid;
  __builtin_amdgcn_global_load_lds((gvoid*)g, (lvoid*)l, 16, 0, 0);
#else
  *(uint4*)l = *(const uint4*)g;   // sync fallback, correctness-equal
#endif
}

// ---------------------------------------------------------------------------
// Split W into bf16 hi/lo, stored XOR-SWIZZLED (granule g -> g^(k&7), stride
// 64 shorts) so global_load_lds's linear copy lands conflict-managed in LDS.
// Pack bf16 hi/lo of (||c||^2 + 64) per code (positive-key offset folded).
// Also: accumulate DECAY * sum(cluster_size) into 8 spread partial slots —
// sum(counts) == N_TOK exactly, so n = 0.9*sum(cs) + 0.1*N is known before
// the argmin runs (lets finalize_cs/finalize_w fuse into one kernel).
__global__ void vq_prep(const float* __restrict__ w, const float* __restrict__ cs,
                        float* __restrict__ ws) {
  const int tid = threadIdx.x;
  const int d = tid & 63;                 // dim
  const int k = blockIdx.x * 4 + (tid >> 6);
  const float v = w[(size_t)k * D_DIM + d];
  const unsigned short h = bf16rne(v);
  const float hf = __uint_as_float((unsigned int)h << 16);
  const unsigned short l = bf16rne(v - hf);
  unsigned short* whi = (unsigned short*)(ws + WS_WHI);
  unsigned short* wlo = (unsigned short*)(ws + WS_WLO);
  const int pos = k * D_DIM + (((d >> 3) ^ (k & 7)) * 8) + (d & 7);
  whi[pos] = h;
  wlo[pos] = l;
  float s = v * v;
#pragma unroll
  for (int m = 32; m >= 1; m >>= 1) s += __shfl_xor(s, m);
  if (d == 0) {
    const float cn64 = s + 64.0f;
    const unsigned short ch = bf16rne(cn64);
    const float chf = __uint_as_float((unsigned int)ch << 16);
    const unsigned short cl = bf16rne(cn64 - chf);
    ((unsigned int*)(ws + WS_CNP))[k] = (unsigned int)ch | ((unsigned int)cl << 16);
    // NSUM partials: 8 spread slots (1024 atomics/slot, parallel across L2)
    atomicAdd(ws + WS_NSUM + (k & 7), DECAY * cs[k]);
  }
}

// ---------------------------------------------------------------------------
// Fused split-bf16 MFMA distance + argmin + segment-sum scatter.
// Block = 8 waves = 4 token-groups(32 tok) x 2 code-halves; 128 tokens/block.
// Grid 512, 2 blocks/CU, 16 waves/CU = 4 waves/SIMD.
//
// R8 change: counted-vmcnt pipeline (T3+T4). 4 LDS stage buffers (64 KB),
// DMA prefetch 2 stages ahead, ONE raw s_barrier per stage preceded by
// s_waitcnt vmcnt(6) — never vmcnt(0) in the loop, so prefetch loads stay
// in flight across barriers (the __syncthreads drain was the m97-style
// ~55% stall: MfmaUtil 44% vs 90 us MFMA floor).
// vmcnt(6) derivation: per-iteration "memory" fences pin each iter's vm ops
// into its region; ops younger than stage-s's DMA pair at the wait point are
// exactly {cnq(s), DMA(s+1) x2} (iter s-1) + {cnq(s+1), DMA(s+2) x2} (iter s)
// = 6. In-order vmcnt retire => vmcnt(6) retires DMA(s) and nothing newer.
// Buffer reuse: DMA issued at iter s writes buf (s+2)%4, last read at iter
// s-2; all waves passed iter s-1's barrier (having consumed those ds_reads
// via lgkm before it) => no overwrite race. Branchless wrap keeps the vm-op
// count uniform in every iteration (tail DMAs land in dead buffers).
//
// Per stage per wave: 13 MFMAs — chain head folds (||c||^2+64) via A=1.0 at
// k-slots 0,1 and B=packed cn hi/lo (same-slot => k-permutation-proof), then
// 12 accumulate (-2zh)*ch + (-2zl)*ch + (-2zh)*cl. acc[r] IS the positive
// distance+64; epilogue = 2 VALU/elem via packed key (low byte = stage id,
// giving first-occurrence tie-break).
__global__ __launch_bounds__(512, 4) void vq_argmin(
    const float* __restrict__ z, float* __restrict__ ws)
{
  __shared__ __align__(16) unsigned short Wbuf[2][4][2][32 * 64]; // [half][buf][plane]
  __shared__ float mind_s[2][128];
  __shared__ int   tok_s[2][128];

  const int tid  = threadIdx.x;
  const int w    = tid >> 6;    // wave 0..7
  const int lane = tid & 63;
  const int m    = lane & 31;   // A row (token) / B col (code) in tile
  const int h    = lane >> 5;   // k-half selector
  const int tg   = w & 3;       // token group (32 tokens)
  const int hw   = w >> 2;      // code half (4096 codes)
  const int tb   = blockIdx.x * 128;

  const unsigned short* whi = (const unsigned short*)(ws + WS_WHI);
  const unsigned short* wlo = (const unsigned short*)(ws + WS_WLO);
  const unsigned int*   cnp = (const unsigned int*)(ws + WS_CNP);

  // ---- A fragments: bf16 hi/lo split of -2*z for this wave's 32 rows ----
  short8 ah[4], al[4];
  float znorm = 0.f;
  {
    const float* zrow = z + (size_t)(tb + tg * 32 + m) * D_DIM + 8 * h;
#pragma unroll
    for (int s4 = 0; s4 < 4; ++s4) {
      const float4 v0 = *(const float4*)(zrow + 16 * s4);
      const float4 v1 = *(const float4*)(zrow + 16 * s4 + 4);
      const float vals[8] = {v0.x, v0.y, v0.z, v0.w, v1.x, v1.y, v1.z, v1.w};
#pragma unroll
      for (int j = 0; j < 8; ++j) {
        const float x = vals[j];
        znorm += x * x;
        const float y = -2.0f * x;
        const unsigned short hb = bf16rne(y);
        const float hf = __uint_as_float((unsigned int)hb << 16);
        const unsigned short lb = bf16rne(y - hf);
        ah[s4][j] = (short)hb;
        al[s4][j] = (short)lb;
      }
    }
    znorm += __shfl_xor(znorm, 32);   // other k-half of the same token row
  }

  // A operand for the cn-fold chain head: bf16 1.0 at k-slots 0,1 on h==0
  short8 acn;
  {
    uint4 ab = {0u, 0u, 0u, 0u};
    ab.x = (h == 0) ? 0x3F803F80u : 0u;
    acn = __builtin_bit_cast(short8, ab);
  }

  float kmin[16];
#pragma unroll
  for (int r = 0; r < 16; ++r) kmin[r] = 3.4e38f;

  // ---- DMA staging: stage = 16 KB as 16 x 1KB segments; wave w moves
  // segments 2w, 2w+1. seg t: half=t>>3, plane=(t>>2)&1, quarter=t&3.
  auto issueStage = [&](int sIdx, int bufIdx) {
#pragma unroll
    for (int i = 0; i < 2; ++i) {
      const int t = w * 2 + i;
      const int half = t >> 3, plane = (t >> 2) & 1, seg = t & 3;
      const unsigned short* src = (plane ? wlo : whi)
          + ((size_t)half * 4096 + (size_t)sIdx * 32) * D_DIM + seg * 512 + lane * 8;
      unsigned short* dst = &Wbuf[half][bufIdx][plane][seg * 512];  // wave-uniform
      gload_lds16(src, dst);
    }
  };

  // precomputed per-lane B read offsets (shorts) into the pre-swizzled rows
  int xoff[4];
#pragma unroll
  for (int s4 = 0; s4 < 4; ++s4) xoff[s4] = ((2 * s4 + h) ^ (m & 7)) * 8;
  const int mrow = m * 64;

  // prologue: 2-deep DMA prefetch + cn prefetch for stage 0
  issueStage(0, 0);
  issueStage(1, 1);
  unsigned int cnq_cur = cnp[hw * 4096 + m];

  const floatx16 kZero = {};

  for (int s = 0; s < 128; ++s) {
    const int b = s & 3;
    // prefetches for this iteration's region (1 cnq + 2 DMA, always)
    const unsigned int cnq_next = cnp[hw * 4096 + ((s + 1) & 127) * 32 + m];
    issueStage((s + 2) & 127, (s + 2) & 3);

    // counted wait: stage-s DMA retired, stage s+1/s+2 stay in flight
    asm volatile("s_waitcnt vmcnt(6)" ::: "memory");
    __builtin_amdgcn_s_barrier();
    asm volatile("" ::: "memory");   // no ds_read hoisting above the barrier

    short8 bh[4], bl[4];
#pragma unroll
    for (int s4 = 0; s4 < 4; ++s4) {
      bh[s4] = *(const short8*)&Wbuf[hw][b][0][mrow + xoff[s4]];
      bl[s4] = *(const short8*)&Wbuf[hw][b][1][mrow + xoff[s4]];
    }
    short8 bcn;
    {
      uint4 bb = {0u, 0u, 0u, 0u};
      bb.x = (h == 0) ? cnq_cur : 0u;
      bcn = __builtin_bit_cast(short8, bb);
    }

    __builtin_amdgcn_s_setprio(1);
    floatx16 acc = MFMA(acn, bcn, kZero);   // acc = ||c||^2 + 64  (per col)
#pragma unroll
    for (int s4 = 0; s4 < 4; ++s4) acc = MFMA(ah[s4], bh[s4], acc);  // -2zh.ch
#pragma unroll
    for (int s4 = 0; s4 < 4; ++s4) acc = MFMA(al[s4], bh[s4], acc);  // -2zl.ch
#pragma unroll
    for (int s4 = 0; s4 < 4; ++s4) acc = MFMA(ah[s4], bl[s4], acc);  // -2zh.cl
    __builtin_amdgcn_s_setprio(0);

    // packed-key argmin: acc[r] > 0; low byte := stage id (ascending =>
    // first-occurrence tie-break at 2^-9 relative precision)
#pragma unroll
    for (int r = 0; r < 16; ++r) {
      kmin[r] = fminf(kmin[r],
          __uint_as_float((__float_as_uint(acc[r]) & 0xFFFFFF00u) | (unsigned)s));
    }
    cnq_cur = cnq_next;
  }

  // ---- reduce over the 32 code-cols per row, carrying origin lane ----
#pragma unroll
  for (int r = 0; r < 16; ++r) {
    float kv = kmin[r];
    int mo = m;
#pragma unroll
    for (int mm = 1; mm < 32; mm <<= 1) {
      const float ov = __shfl_xor(kv, mm);
      const int   om = __shfl_xor(mo, mm);
      if (ov < kv || (ov == kv && om < mo)) { kv = ov; mo = om; }
    }
    // C/D layout: row = (r&3) + 8*(r>>2) + 4*h. One writer lane per row.
    const int mr = (r & 3) + 8 * (r >> 2) + 4 * h;
    if (m == mr) {
      const unsigned int kb = __float_as_uint(kv);
      tok_s[hw][tg * 32 + mr] = hw * 4096 + (int)(kb & 0xFFu) * 32 + mo;
      mind_s[hw][tg * 32 + mr] =
          __uint_as_float(kb & 0xFFFFFF00u) - 64.0f + znorm;
    }
  }
  __syncthreads();

  float* counts = ws + WS_COUNTS;
  float* embsum = ws + WS_EMBSUM;

  // merge code-halves (strict '<' keeps half0 on ties), qe partial + counts
  if (tid < 128) {
    const float d0 = mind_s[0][tid], d1 = mind_s[1][tid];
    const int   i0 = tok_s[0][tid],  i1 = tok_s[1][tid];
    const bool t1 = d1 < d0;
    const float dm = t1 ? d1 : d0;
    const int   im = t1 ? i1 : i0;
    tok_s[0][tid] = im;
    float qe = dm;
#pragma unroll
    for (int mm = 32; mm >= 1; mm >>= 1) qe += __shfl_xor(qe, mm);
    if ((tid & 63) == 0) atomicAdd(ws + WS_QE, qe);
    atomicAdd(&counts[im], 1.0f);
  }
  __syncthreads();

  // segment-sum of z: wave-coalesced atomics (64 consecutive floats/instr)
#pragma unroll 4
  for (int t = 0; t < 16; ++t) {
    const int row = w * 16 + t;
    const int tk = tok_s[0][row];
    const float zv = z[(size_t)(tb + row) * D_DIM + lane];
    atomicAdd(&embsum[(size_t)tk * D_DIM + lane], zv);
  }
}

// ---------------------------------------------------------------------------
// Fused finalize: n = 0.9*sum(cs) + 0.1*N_TOK is precomputed by vq_prep
// (sum(counts) == N_TOK exactly), so ncs/nea/weight all finalize in one pass.
// One wave spans exactly one code k (64 dims) => cs/counts loads broadcast.
__global__ void vq_finalize(const float* __restrict__ cluster_size,
                            const float* __restrict__ embed_avg,
                            const float* __restrict__ ws, float* __restrict__ out)
{
  const int idx = blockIdx.x * 256 + threadIdx.x;   // over K*D
  const int k = idx >> 6;
  const float ncs = cluster_size[k] * DECAY + OMD * ws[WS_COUNTS + k];
  const float nea = embed_avg[idx] * DECAY + OMD * ws[WS_EMBSUM + idx];
  out[OUT_EA + idx] = nea;
  float n = OMD * (float)N_TOK;
#pragma unroll
  for (int i = 0; i < 8; ++i) n += ws[WS_NSUM + i];
  const float sm = (ncs + EPS) / (n + K_CODE * EPS) * n;
  out[OUT_W + idx] = nea / sm;
  if ((idx & 63) == 0) out[OUT_CS + k] = ncs;
  if (idx == 0) out[OUT_QE] = ws[WS_QE] * (1.0f / N_TOK);
}

// ---------------------------------------------------------------------------
extern "C" void kernel_launch(void* const* d_in, const int* in_sizes, int n_in,
                              void* d_out, int out_size, void* d_ws, size_t ws_size,
                              hipStream_t stream) {
  const float* z  = (const float*)d_in[0];
  const float* w  = (const float*)d_in[1];
  const float* cs = (const float*)d_in[2];
  const float* ea = (const float*)d_in[3];
  float* out = (float*)d_out;
  float* ws  = (float*)d_ws;

  (void)hipMemsetAsync(d_ws, 0, (size_t)WS_ZERO * sizeof(float), stream);

  vq_prep<<<K_CODE / 4, 256, 0, stream>>>(w, cs, ws);
  vq_argmin<<<N_TOK / 128, 512, 0, stream>>>(z, ws);
  vq_finalize<<<K_CODE * D_DIM / 256, 256, 0, stream>>>(cs, ea, ws, out);
}

// Round 2
// 357.104 us; speedup vs baseline: 1.0774x; 1.0774x over previous
//
#include <hip/hip_runtime.h>
#include <type_traits>

#define N_TOK 65536
#define K_CODE 8192
#define D_DIM 64

constexpr float DECAY = 0.9f;
constexpr float OMD = 0.1f;   // 1 - DECAY
constexpr float EPS = 1e-5f;

// ---- output layout (floats), per reference return order ----
constexpr int OUT_QE = 0;
constexpr int OUT_W  = 1;
constexpr int OUT_CS = 1 + K_CODE * D_DIM;
constexpr int OUT_EA = OUT_CS + K_CODE;

// ---- workspace layout (floats) ----
constexpr int WS_QE     = 0;
constexpr int WS_NSUM   = 16;                           // 8 slots, stride 32 floats (128B apart)
constexpr int WS_COUNTS = 16 + 8 * 32;                  // 272
constexpr int WS_EMBSUM = WS_COUNTS + K_CODE;
constexpr int WS_WHI    = WS_EMBSUM + K_CODE * D_DIM;   // ushort[K*64] bf16 hi, XOR-swizzled
constexpr int WS_WLO    = WS_WHI + K_CODE * D_DIM / 2;  // ushort[K*64] bf16 lo, XOR-swizzled
constexpr int WS_CNF    = WS_WLO + K_CODE * D_DIM / 2;  // float[K]: ||c||^2 + 64 (exact f32)
constexpr int WS_ZERO   = WS_WHI;                       // floats to memset

typedef __attribute__((ext_vector_type(16))) float floatx16;
typedef __attribute__((ext_vector_type(8)))  short short8;
typedef __attribute__((ext_vector_type(8)))  __bf16 bf16x8;

// SFINAE hedge: mfma bf16 builtin takes v8bf16 on newer clang, v8i16 on older.
template <typename T, typename = void> struct mfma_takes : std::false_type {};
template <typename T>
struct mfma_takes<T, std::void_t<decltype(__builtin_amdgcn_mfma_f32_32x32x16_bf16(
    std::declval<T>(), std::declval<T>(), std::declval<floatx16>(), 0, 0, 0))>>
    : std::true_type {};

__device__ __forceinline__ floatx16 MFMA(short8 a, short8 b, floatx16 c) {
  if constexpr (mfma_takes<bf16x8>::value) {
    return __builtin_amdgcn_mfma_f32_32x32x16_bf16(
        __builtin_bit_cast(bf16x8, a), __builtin_bit_cast(bf16x8, b), c, 0, 0, 0);
  } else {
    return __builtin_amdgcn_mfma_f32_32x32x16_bf16(a, b, c, 0, 0, 0);
  }
}

__device__ __forceinline__ unsigned short bf16rne(float x) {
  unsigned int u = __float_as_uint(x);
  return (unsigned short)((u + 0x7FFFu + ((u >> 16) & 1u)) >> 16);
}

// async global->LDS 16B DMA (HW writes LDS at wave-uniform dst + lane*16)
__device__ __forceinline__ void gload_lds16(const unsigned short* g, unsigned short* l) {
#if defined(__has_builtin) && __has_builtin(__builtin_amdgcn_global_load_lds)
  typedef __attribute__((address_space(1))) void gvoid;
  typedef __attribute__((address_space(3))) void lvoid;
  __builtin_amdgcn_global_load_lds((gvoid*)g, (lvoid*)l, 16, 0, 0);
#else
  *(uint4*)l = *(const uint4*)g;   // sync fallback (builtin exists on gfx950)
#endif
}

// ---------------------------------------------------------------------------
// Split W into bf16 hi/lo, stored XOR-SWIZZLED (granule g -> g^(k&7), stride
// 64 shorts) so global_load_lds's linear copy lands conflict-managed in LDS.
// Store ||c||^2 + 64 as exact f32 (R2: acc is initialized by f32 splat, the
// chain-head MFMA is gone). NSUM: one atomic per block into 8 line-spread
// slots (R1's 8192 same-line atomics serialized at one TCC channel).
__global__ void vq_prep(const float* __restrict__ w, const float* __restrict__ cs,
                        float* __restrict__ ws) {
  const int tid = threadIdx.x;
  const int d = tid & 63;                 // dim
  const int kw = tid >> 6;                // 0..3
  const int k = blockIdx.x * 4 + kw;
  const float v = w[(size_t)k * D_DIM + d];
  const unsigned short h = bf16rne(v);
  const float hf = __uint_as_float((unsigned int)h << 16);
  const unsigned short l = bf16rne(v - hf);
  unsigned short* whi = (unsigned short*)(ws + WS_WHI);
  unsigned short* wlo = (unsigned short*)(ws + WS_WLO);
  const int pos = k * D_DIM + (((d >> 3) ^ (k & 7)) * 8) + (d & 7);
  whi[pos] = h;
  wlo[pos] = l;
  float s = v * v;
#pragma unroll
  for (int m = 32; m >= 1; m >>= 1) s += __shfl_xor(s, m);
  __shared__ float csp[4];
  if (d == 0) {
    (ws + WS_CNF)[k] = s + 64.0f;
    csp[kw] = cs[k];
  }
  __syncthreads();
  if (tid == 0) {
    atomicAdd(ws + WS_NSUM + ((blockIdx.x & 7) << 5),
              DECAY * (csp[0] + csp[1] + csp[2] + csp[3]));
  }
}

// ---------------------------------------------------------------------------
// Fused split-bf16 MFMA distance + argmin + segment-sum scatter.
// Block = 8 waves = 4 token-groups(32 tok) x 2 code-halves; 128 tokens/block.
// Grid 512, 2 blocks/CU, 16 waves/CU = 4 waves/SIMD.
//
// R2: register READ-AHEAD pipeline. R1's counted-vmcnt alone was neutral
// (227us, MfmaUtil 45%): the stall is the 2-phase lockstep — every stage all
// 16 waves/CU issue 8 ds_read_b128 at once (~2000 cyc through the shared LDS
// pipe, MFMA idle), then all MFMA. Fix = ds_read stage s+1's B-hi (+ stage
// s's B-lo) BEFORE stage s's MFMAs, so MFMAs consume registers read a full
// stage earlier and the LDS pipe overlaps the MFMA pipe. B-hi is register-
// double-buffered; B-lo single-buffered (first use is after 8 MFMAs ~256cy,
// enough cover) to stay <=128 VGPR (2 blocks/CU).
//
// Per stage per wave: 12 MFMAs (R2: chain-head dropped — C/D layout gives
// every acc element of a lane the SAME column (code), so ||c||^2+64 is a
// per-lane f32 scalar; acc init = splat, exact). Terms: (-2zh)*ch +
// (-2zl)*ch + (-2zh)*cl. Epilogue packed key (low byte = stage id).
//
// vmcnt(3) per half-stage: regions are fenced (memory-clobber asm), each
// region issues exactly {2 DMA, 1 cnf load}; worst-case intra-region order
// still leaves the needed DMA pair retired at <=3 outstanding. DMA(s+2) is
// issued at iter s, consumed (ds_read) at iter s+1 => 1 full stage of
// landing window. Barrier every stage is REQUIRED: wave A reads segments
// DMA'd by wave B; B's vmcnt wait + barrier is A's only visibility guarantee.
// Buffer reuse: 4 bufs, skew <=1 stage (per-stage barrier) => DMA target
// (s+2)&3 never collides with any wave's live reads (s&3, (s+1)&3).
__global__ __launch_bounds__(512, 4) void vq_argmin(
    const float* __restrict__ z, float* __restrict__ ws)
{
  __shared__ __align__(16) unsigned short Wbuf[2][4][2][32 * 64]; // [half][buf][plane]
  __shared__ float mind_s[2][128];
  __shared__ int   tok_s[2][128];

  const int tid  = threadIdx.x;
  const int w    = tid >> 6;    // wave 0..7
  const int lane = tid & 63;
  const int m    = lane & 31;   // A row (token) / B col (code) in tile
  const int h    = lane >> 5;   // k-half selector
  const int tg   = w & 3;       // token group (32 tokens)
  const int hw   = w >> 2;      // code half (4096 codes)
  const int tb   = blockIdx.x * 128;

  const unsigned short* whi = (const unsigned short*)(ws + WS_WHI);
  const unsigned short* wlo = (const unsigned short*)(ws + WS_WLO);
  const float*          cnf = ws + WS_CNF;

  // ---- A fragments: bf16 hi/lo split of -2*z for this wave's 32 rows ----
  short8 ah[4], al[4];
  float znorm = 0.f;
  {
    const float* zrow = z + (size_t)(tb + tg * 32 + m) * D_DIM + 8 * h;
#pragma unroll
    for (int s4 = 0; s4 < 4; ++s4) {
      const float4 v0 = *(const float4*)(zrow + 16 * s4);
      const float4 v1 = *(const float4*)(zrow + 16 * s4 + 4);
      const float vals[8] = {v0.x, v0.y, v0.z, v0.w, v1.x, v1.y, v1.z, v1.w};
#pragma unroll
      for (int j = 0; j < 8; ++j) {
        const float x = vals[j];
        znorm += x * x;
        const float y = -2.0f * x;
        const unsigned short hb = bf16rne(y);
        const float hf = __uint_as_float((unsigned int)hb << 16);
        const unsigned short lb = bf16rne(y - hf);
        ah[s4][j] = (short)hb;
        al[s4][j] = (short)lb;
      }
    }
    znorm += __shfl_xor(znorm, 32);   // other k-half of the same token row
  }

  float kmin[16];
#pragma unroll
  for (int r = 0; r < 16; ++r) kmin[r] = 3.4e38f;

  // ---- DMA staging: stage = 16 KB as 16 x 1KB segments; wave w moves
  // segments 2w, 2w+1. seg t: half=t>>3, plane=(t>>2)&1, quarter=t&3.
  auto issueStage = [&](int sIdx, int bufIdx) {
#pragma unroll
    for (int i = 0; i < 2; ++i) {
      const int t = w * 2 + i;
      const int half = t >> 3, plane = (t >> 2) & 1, seg = t & 3;
      const unsigned short* src = (plane ? wlo : whi)
          + ((size_t)half * 4096 + (size_t)sIdx * 32) * D_DIM + seg * 512 + lane * 8;
      unsigned short* dst = &Wbuf[half][bufIdx][plane][seg * 512];  // wave-uniform
      gload_lds16(src, dst);
    }
  };

  // precomputed per-lane B read offsets (shorts) into the pre-swizzled rows
  int xoff[4];
#pragma unroll
  for (int s4 = 0; s4 < 4; ++s4) xoff[s4] = ((2 * s4 + h) ^ (m & 7)) * 8;
  const int mrow = m * 64;
  const int cbase = hw * 4096;

#define LOADBH(BH, BUF) do {                                          \
    const unsigned short* _p = &Wbuf[hw][(BUF)][0][mrow];             \
    BH[0] = *(const short8*)(_p + xoff[0]);                           \
    BH[1] = *(const short8*)(_p + xoff[1]);                           \
    BH[2] = *(const short8*)(_p + xoff[2]);                           \
    BH[3] = *(const short8*)(_p + xoff[3]);                           \
  } while (0)

#define LOADBL(BL, BUF) do {                                          \
    const unsigned short* _p = &Wbuf[hw][(BUF)][1][mrow];             \
    BL[0] = *(const short8*)(_p + xoff[0]);                           \
    BL[1] = *(const short8*)(_p + xoff[1]);                           \
    BL[2] = *(const short8*)(_p + xoff[2]);                           \
    BL[3] = *(const short8*)(_p + xoff[3]);                           \
  } while (0)

  // acc init = f32 splat of ||c||^2+64 (per-lane scalar: all 16 C/D elems of
  // a lane share column m). 12 MFMAs; bl-terms last (covers bl ds latency).
#define COMPUTE(BH, BL, CN, SID) do {                                          \
    floatx16 acc;                                                              \
    _Pragma("unroll") for (int r = 0; r < 16; ++r) acc[r] = (CN);              \
    __builtin_amdgcn_s_setprio(1);                                             \
    acc = MFMA(ah[0], BH[0], acc); acc = MFMA(ah[1], BH[1], acc);              \
    acc = MFMA(ah[2], BH[2], acc); acc = MFMA(ah[3], BH[3], acc);              \
    acc = MFMA(al[0], BH[0], acc); acc = MFMA(al[1], BH[1], acc);              \
    acc = MFMA(al[2], BH[2], acc); acc = MFMA(al[3], BH[3], acc);              \
    acc = MFMA(ah[0], BL[0], acc); acc = MFMA(ah[1], BL[1], acc);              \
    acc = MFMA(ah[2], BL[2], acc); acc = MFMA(ah[3], BL[3], acc);              \
    __builtin_amdgcn_s_setprio(0);                                             \
    _Pragma("unroll") for (int r = 0; r < 16; ++r)                             \
      kmin[r] = fminf(kmin[r],                                                 \
          __uint_as_float((__float_as_uint(acc[r]) & 0xFFFFFF00u)              \
                          | (unsigned)(SID)));                                 \
  } while (0)

  // ---- prologue: 2 stages of DMA, drain once, prime bh0 ----
  issueStage(0, 0);
  issueStage(1, 1);
  float cn0 = cnf[cbase + m];
  float cn1 = 0.f;
  asm volatile("s_waitcnt vmcnt(0)" ::: "memory");
  __builtin_amdgcn_s_barrier();
  asm volatile("" ::: "memory");

  short8 bh0[4], bh1[4], bl[4];
  LOADBH(bh0, 0);

  for (int s = 0; s < 128; s += 2) {
    // ---- even half: compute stage s (bh0), read-ahead bh1 <- stage s+1 ----
    issueStage((s + 2) & 127, (s + 2) & 3);
    cn1 = cnf[cbase + ((s + 1) & 127) * 32 + m];
    asm volatile("s_waitcnt vmcnt(3)" ::: "memory");
    __builtin_amdgcn_s_barrier();
    asm volatile("" ::: "memory");
    LOADBL(bl, s & 3);
    LOADBH(bh1, (s + 1) & 3);
    COMPUTE(bh0, bl, cn0, s);

    // ---- odd half: compute stage s+1 (bh1), read-ahead bh0 <- stage s+2 ----
    issueStage((s + 3) & 127, (s + 3) & 3);
    cn0 = cnf[cbase + ((s + 2) & 127) * 32 + m];
    asm volatile("s_waitcnt vmcnt(3)" ::: "memory");
    __builtin_amdgcn_s_barrier();
    asm volatile("" ::: "memory");
    LOADBL(bl, (s + 1) & 3);
    LOADBH(bh0, (s + 2) & 3);
    COMPUTE(bh1, bl, cn1, s + 1);
  }
#undef LOADBH
#undef LOADBL
#undef COMPUTE

  // ---- reduce over the 32 code-cols per row, carrying origin lane ----
#pragma unroll
  for (int r = 0; r < 16; ++r) {
    float kv = kmin[r];
    int mo = m;
#pragma unroll
    for (int mm = 1; mm < 32; mm <<= 1) {
      const float ov = __shfl_xor(kv, mm);
      const int   om = __shfl_xor(mo, mm);
      if (ov < kv || (ov == kv && om < mo)) { kv = ov; mo = om; }
    }
    // C/D layout: row = (r&3) + 8*(r>>2) + 4*h. One writer lane per row.
    const int mr = (r & 3) + 8 * (r >> 2) + 4 * h;
    if (m == mr) {
      const unsigned int kb = __float_as_uint(kv);
      tok_s[hw][tg * 32 + mr] = hw * 4096 + (int)(kb & 0xFFu) * 32 + mo;
      mind_s[hw][tg * 32 + mr] =
          __uint_as_float(kb & 0xFFFFFF00u) - 64.0f + znorm;
    }
  }
  __syncthreads();

  float* counts = ws + WS_COUNTS;
  float* embsum = ws + WS_EMBSUM;

  // merge code-halves (strict '<' keeps half0 on ties), qe partial + counts
  if (tid < 128) {
    const float d0 = mind_s[0][tid], d1 = mind_s[1][tid];
    const int   i0 = tok_s[0][tid],  i1 = tok_s[1][tid];
    const bool t1 = d1 < d0;
    const float dm = t1 ? d1 : d0;
    const int   im = t1 ? i1 : i0;
    tok_s[0][tid] = im;
    float qe = dm;
#pragma unroll
    for (int mm = 32; mm >= 1; mm >>= 1) qe += __shfl_xor(qe, mm);
    if ((tid & 63) == 0) atomicAdd(ws + WS_QE, qe);
    atomicAdd(&counts[im], 1.0f);
  }
  __syncthreads();

  // segment-sum of z: wave-coalesced atomics (64 consecutive floats/instr)
#pragma unroll 4
  for (int t = 0; t < 16; ++t) {
    const int row = w * 16 + t;
    const int tk = tok_s[0][row];
    const float zv = z[(size_t)(tb + row) * D_DIM + lane];
    atomicAdd(&embsum[(size_t)tk * D_DIM + lane], zv);
  }
}

// ---------------------------------------------------------------------------
// Fused finalize: n = 0.9*sum(cs) + 0.1*N_TOK is precomputed by vq_prep
// (sum(counts) == N_TOK exactly), so ncs/nea/weight all finalize in one pass.
__global__ void vq_finalize(const float* __restrict__ cluster_size,
                            const float* __restrict__ embed_avg,
                            const float* __restrict__ ws, float* __restrict__ out)
{
  const int idx = blockIdx.x * 256 + threadIdx.x;   // over K*D
  const int k = idx >> 6;
  const float ncs = cluster_size[k] * DECAY + OMD * ws[WS_COUNTS + k];
  const float nea = embed_avg[idx] * DECAY + OMD * ws[WS_EMBSUM + idx];
  out[OUT_EA + idx] = nea;
  float n = OMD * (float)N_TOK;
#pragma unroll
  for (int i = 0; i < 8; ++i) n += ws[WS_NSUM + (i << 5)];
  const float sm = (ncs + EPS) / (n + K_CODE * EPS) * n;
  out[OUT_W + idx] = nea / sm;
  if ((idx & 63) == 0) out[OUT_CS + k] = ncs;
  if (idx == 0) out[OUT_QE] = ws[WS_QE] * (1.0f / N_TOK);
}

// ---------------------------------------------------------------------------
extern "C" void kernel_launch(void* const* d_in, const int* in_sizes, int n_in,
                              void* d_out, int out_size, void* d_ws, size_t ws_size,
                              hipStream_t stream) {
  const float* z  = (const float*)d_in[0];
  const float* w  = (const float*)d_in[1];
  const float* cs = (const float*)d_in[2];
  const float* ea = (const float*)d_in[3];
  float* out = (float*)d_out;
  float* ws  = (float*)d_ws;

  (void)hipMemsetAsync(d_ws, 0, (size_t)WS_ZERO * sizeof(float), stream);

  vq_prep<<<K_CODE / 4, 256, 0, stream>>>(w, cs, ws);
  vq_argmin<<<N_TOK / 128, 512, 0, stream>>>(z, ws);
  vq_finalize<<<K_CODE * D_DIM / 256, 256, 0, stream>>>(cs, ea, ws, out);
}

// Round 4
// 271.274 us; speedup vs baseline: 1.4183x; 1.3164x over previous
//
#include <hip/hip_runtime.h>
#include <type_traits>

#define N_TOK 65536
#define K_CODE 8192
#define D_DIM 64

constexpr float DECAY = 0.9f;
constexpr float OMD = 0.1f;   // 1 - DECAY
constexpr float EPS = 1e-5f;

// ---- output layout (floats), per reference return order ----
constexpr int OUT_QE = 0;
constexpr int OUT_W  = 1;
constexpr int OUT_CS = 1 + K_CODE * D_DIM;
constexpr int OUT_EA = OUT_CS + K_CODE;

// ---- workspace layout (floats) ----
constexpr int WS_QE     = 0;
constexpr int WS_NSUM   = 16;                           // 8 slots, stride 32 floats (128B apart)
constexpr int WS_COUNTS = 16 + 8 * 32;                  // 272
constexpr int WS_EMBSUM = WS_COUNTS + K_CODE;
constexpr int WS_WHI    = WS_EMBSUM + K_CODE * D_DIM;   // ushort[K*64] bf16 hi, XOR-swizzled
constexpr int WS_WLO    = WS_WHI + K_CODE * D_DIM / 2;  // ushort[K*64] bf16 lo, XOR-swizzled
constexpr int WS_CNF    = WS_WLO + K_CODE * D_DIM / 2;  // float[K]: ||c||^2 + 64 (exact f32)
constexpr int WS_ZERO   = WS_WHI;                       // floats to memset

typedef __attribute__((ext_vector_type(16))) float floatx16;
typedef __attribute__((ext_vector_type(8)))  short short8;
typedef __attribute__((ext_vector_type(8)))  __bf16 bf16x8;

// SFINAE hedge: mfma bf16 builtin takes v8bf16 on newer clang, v8i16 on older.
template <typename T, typename = void> struct mfma_takes : std::false_type {};
template <typename T>
struct mfma_takes<T, std::void_t<decltype(__builtin_amdgcn_mfma_f32_32x32x16_bf16(
    std::declval<T>(), std::declval<T>(), std::declval<floatx16>(), 0, 0, 0))>>
    : std::true_type {};

__device__ __forceinline__ floatx16 MFMA(short8 a, short8 b, floatx16 c) {
  if constexpr (mfma_takes<bf16x8>::value) {
    return __builtin_amdgcn_mfma_f32_32x32x16_bf16(
        __builtin_bit_cast(bf16x8, a), __builtin_bit_cast(bf16x8, b), c, 0, 0, 0);
  } else {
    return __builtin_amdgcn_mfma_f32_32x32x16_bf16(a, b, c, 0, 0, 0);
  }
}

__device__ __forceinline__ unsigned short bf16rne(float x) {
  unsigned int u = __float_as_uint(x);
  return (unsigned short)((u + 0x7FFFu + ((u >> 16) & 1u)) >> 16);
}

// async global->LDS 16B DMA (HW writes LDS at wave-uniform dst + lane*16)
__device__ __forceinline__ void gload_lds16(const unsigned short* g, unsigned short* l) {
#if defined(__has_builtin) && __has_builtin(__builtin_amdgcn_global_load_lds)
  typedef __attribute__((address_space(1))) void gvoid;
  typedef __attribute__((address_space(3))) void lvoid;
  __builtin_amdgcn_global_load_lds((gvoid*)g, (lvoid*)l, 16, 0, 0);
#else
  *(uint4*)l = *(const uint4*)g;   // sync fallback (builtin exists on gfx950)
#endif
}

// ---------------------------------------------------------------------------
// Split W into bf16 hi/lo, stored XOR-SWIZZLED (granule g -> g^(k&7), stride
// 64 shorts) so global_load_lds's linear copy lands conflict-managed in LDS.
// Store ||c||^2 + 64 as exact f32 (acc is initialized by f32 splat). NSUM:
// one atomic per block into 8 line-spread slots.
__global__ void vq_prep(const float* __restrict__ w, const float* __restrict__ cs,
                        float* __restrict__ ws) {
  const int tid = threadIdx.x;
  const int d = tid & 63;                 // dim
  const int kw = tid >> 6;                // 0..3
  const int k = blockIdx.x * 4 + kw;
  const float v = w[(size_t)k * D_DIM + d];
  const unsigned short h = bf16rne(v);
  const float hf = __uint_as_float((unsigned int)h << 16);
  const unsigned short l = bf16rne(v - hf);
  unsigned short* whi = (unsigned short*)(ws + WS_WHI);
  unsigned short* wlo = (unsigned short*)(ws + WS_WLO);
  const int pos = k * D_DIM + (((d >> 3) ^ (k & 7)) * 8) + (d & 7);
  whi[pos] = h;
  wlo[pos] = l;
  float s = v * v;
#pragma unroll
  for (int m = 32; m >= 1; m >>= 1) s += __shfl_xor(s, m);
  __shared__ float csp[4];
  if (d == 0) {
    (ws + WS_CNF)[k] = s + 64.0f;
    csp[kw] = cs[k];
  }
  __syncthreads();
  if (tid == 0) {
    atomicAdd(ws + WS_NSUM + ((blockIdx.x & 7) << 5),
              DECAY * (csp[0] + csp[1] + csp[2] + csp[3]));
  }
}

// ---------------------------------------------------------------------------
// Fused split-bf16 MFMA distance + argmin + segment-sum scatter.
// Block = 8 waves = 4 token-groups(32 tok) x 2 code-halves; 128 tokens/block.
// Grid 512, 2 blocks/CU, 16 waves/CU = 4 waves/SIMD.
//
// R4 == R3 resubmit (container failed twice; no measurement was taken).
//
// R3: read-ahead pipeline WITHOUT register double-buffer (R2 spilled:
// WRITE_SIZE 18MB->644MB, ~5 VGPR/thread-stage of scratch; 112-reg working
// set + temps > the 128-VGPR cap of launch_bounds(512,4)).
// Stage MFMAs split into G1=ah*bh(4), G2=al*bh(4), G3=ah*bl(4); bh dies
// after G2, so ONE bh buffer suffices: LOADBH(bh, s+1) sits after G2 and the
// register WAR dependency pins it there. Cover: bh(s+1) reads overlap
// G3+kmin+barrier (~250cy); bl(s) reads (issued right after the barrier)
// overlap G1+G2 (~256cy). LDS pipe thus runs concurrently with the MFMA
// pipe every stage — the R1 lockstep stall (all 16 waves storm LDS, then
// all MFMA) is what capped MfmaUtil at 44%.
//
// Per stage per wave: 12 MFMAs (chain-head folded: C/D layout gives every
// acc element of a lane the SAME column (code), so ||c||^2+64 is a per-lane
// f32 scalar; acc init = splat, exact). Terms: (-2zh)*ch + (-2zl)*ch +
// (-2zh)*cl; dropped (-2zl)*cl ~ 2^-16 relative, below the 2^-9 key
// truncation. Epilogue packed key (low byte = stage id, first-occurrence
// tie-break).
//
// vmcnt(3) per region: regions fenced (memory-clobber asm); each region
// issues exactly {2 DMA, 1 cnf load} = 3 vm ops. At region s's wait,
// outstanding <= 3 (prior region, by induction) + 3 (this region) = 6;
// vmcnt(3) retires region s-1's ops incl. DMA(s+1) — exactly what the
// LOADBH(bh,(s+1)&3) at the end of this region needs (own retire + barrier
// = cross-wave visibility). DMA(s+2) is issued 2 stages before its reads.
// Buffer reuse: 4 bufs; reads of buf b in region s complete before that
// wave's kmin update (data dep), hence before barrier(s), hence before any
// wave issues DMA targeting b again (region s+2, after barrier(s+1)).
__global__ __launch_bounds__(512, 4) void vq_argmin(
    const float* __restrict__ z, float* __restrict__ ws)
{
  __shared__ __align__(16) unsigned short Wbuf[2][4][2][32 * 64]; // [half][buf][plane]
  __shared__ float mind_s[2][128];
  __shared__ int   tok_s[2][128];

  const int tid  = threadIdx.x;
  const int w    = tid >> 6;    // wave 0..7
  const int lane = tid & 63;
  const int m    = lane & 31;   // A row (token) / B col (code) in tile
  const int h    = lane >> 5;   // k-half selector
  const int tg   = w & 3;       // token group (32 tokens)
  const int hw   = w >> 2;      // code half (4096 codes)
  const int tb   = blockIdx.x * 128;

  const unsigned short* whi = (const unsigned short*)(ws + WS_WHI);
  const unsigned short* wlo = (const unsigned short*)(ws + WS_WLO);
  const float*          cnf = ws + WS_CNF;

  // ---- A fragments: bf16 hi/lo split of -2*z for this wave's 32 rows ----
  short8 ah[4], al[4];
  float znorm = 0.f;
  {
    const float* zrow = z + (size_t)(tb + tg * 32 + m) * D_DIM + 8 * h;
#pragma unroll
    for (int s4 = 0; s4 < 4; ++s4) {
      const float4 v0 = *(const float4*)(zrow + 16 * s4);
      const float4 v1 = *(const float4*)(zrow + 16 * s4 + 4);
      const float vals[8] = {v0.x, v0.y, v0.z, v0.w, v1.x, v1.y, v1.z, v1.w};
#pragma unroll
      for (int j = 0; j < 8; ++j) {
        const float x = vals[j];
        znorm += x * x;
        const float y = -2.0f * x;
        const unsigned short hb = bf16rne(y);
        const float hf = __uint_as_float((unsigned int)hb << 16);
        const unsigned short lb = bf16rne(y - hf);
        ah[s4][j] = (short)hb;
        al[s4][j] = (short)lb;
      }
    }
    znorm += __shfl_xor(znorm, 32);   // other k-half of the same token row
  }

  float kmin[16];
#pragma unroll
  for (int r = 0; r < 16; ++r) kmin[r] = 3.4e38f;

  // ---- DMA staging: stage = 16 KB as 16 x 1KB segments; wave w moves
  // segments 2w, 2w+1. seg t: half=t>>3, plane=(t>>2)&1, quarter=t&3.
  auto issueStage = [&](int sIdx, int bufIdx) {
#pragma unroll
    for (int i = 0; i < 2; ++i) {
      const int t = w * 2 + i;
      const int half = t >> 3, plane = (t >> 2) & 1, seg = t & 3;
      const unsigned short* src = (plane ? wlo : whi)
          + ((size_t)half * 4096 + (size_t)sIdx * 32) * D_DIM + seg * 512 + lane * 8;
      unsigned short* dst = &Wbuf[half][bufIdx][plane][seg * 512];  // wave-uniform
      gload_lds16(src, dst);
    }
  };

  // precomputed per-lane B read offsets (shorts) into the pre-swizzled rows
  int xoff[4];
#pragma unroll
  for (int s4 = 0; s4 < 4; ++s4) xoff[s4] = ((2 * s4 + h) ^ (m & 7)) * 8;
  const int mrow = m * 64;
  const int cbase = hw * 4096;

#define LOADBH(BH, BUF) do {                                          \
    const unsigned short* _p = &Wbuf[hw][(BUF)][0][mrow];             \
    BH[0] = *(const short8*)(_p + xoff[0]);                           \
    BH[1] = *(const short8*)(_p + xoff[1]);                           \
    BH[2] = *(const short8*)(_p + xoff[2]);                           \
    BH[3] = *(const short8*)(_p + xoff[3]);                           \
  } while (0)

#define LOADBL(BL, BUF) do {                                          \
    const unsigned short* _p = &Wbuf[hw][(BUF)][1][mrow];             \
    BL[0] = *(const short8*)(_p + xoff[0]);                           \
    BL[1] = *(const short8*)(_p + xoff[1]);                           \
    BL[2] = *(const short8*)(_p + xoff[2]);                           \
    BL[3] = *(const short8*)(_p + xoff[3]);                           \
  } while (0)

  // ---- prologue: 2 stages of DMA, drain once, prime bh <- stage 0 ----
  issueStage(0, 0);
  issueStage(1, 1);
  float cn_cur = cnf[cbase + m];
  asm volatile("s_waitcnt vmcnt(0)" ::: "memory");
  __builtin_amdgcn_s_barrier();
  asm volatile("" ::: "memory");

  short8 bh[4], bl[4];
  LOADBH(bh, 0);

  for (int s = 0; s < 128; ++s) {
    // region s: issue exactly {2 DMA, 1 cnf} vm ops (branchless wrap keeps
    // the count uniform; tail DMAs land in dead buffers)
    issueStage((s + 2) & 127, (s + 2) & 3);
    const float cn_next = cnf[cbase + ((s + 1) & 127) * 32 + m];
    asm volatile("s_waitcnt vmcnt(3)" ::: "memory");
    __builtin_amdgcn_s_barrier();
    asm volatile("" ::: "memory");

    LOADBL(bl, s & 3);                       // covered by G1+G2

    floatx16 acc;
#pragma unroll
    for (int r = 0; r < 16; ++r) acc[r] = cn_cur;

    __builtin_amdgcn_s_setprio(1);
    acc = MFMA(ah[0], bh[0], acc); acc = MFMA(ah[1], bh[1], acc);   // G1
    acc = MFMA(ah[2], bh[2], acc); acc = MFMA(ah[3], bh[3], acc);
    acc = MFMA(al[0], bh[0], acc); acc = MFMA(al[1], bh[1], acc);   // G2
    acc = MFMA(al[2], bh[2], acc); acc = MFMA(al[3], bh[3], acc);
    __builtin_amdgcn_s_setprio(0);

    LOADBH(bh, (s + 1) & 3);                 // WAR on bh pins this after G2;
                                             // covered by G3+kmin+barrier
    __builtin_amdgcn_s_setprio(1);
    acc = MFMA(ah[0], bl[0], acc); acc = MFMA(ah[1], bl[1], acc);   // G3
    acc = MFMA(ah[2], bl[2], acc); acc = MFMA(ah[3], bl[3], acc);
    __builtin_amdgcn_s_setprio(0);

    // packed-key argmin: acc[r] > 0; low byte := stage id
#pragma unroll
    for (int r = 0; r < 16; ++r) {
      kmin[r] = fminf(kmin[r],
          __uint_as_float((__float_as_uint(acc[r]) & 0xFFFFFF00u) | (unsigned)s));
    }
    cn_cur = cn_next;
  }
#undef LOADBH
#undef LOADBL

  // ---- reduce over the 32 code-cols per row, carrying origin lane ----
#pragma unroll
  for (int r = 0; r < 16; ++r) {
    float kv = kmin[r];
    int mo = m;
#pragma unroll
    for (int mm = 1; mm < 32; mm <<= 1) {
      const float ov = __shfl_xor(kv, mm);
      const int   om = __shfl_xor(mo, mm);
      if (ov < kv || (ov == kv && om < mo)) { kv = ov; mo = om; }
    }
    // C/D layout: row = (r&3) + 8*(r>>2) + 4*h. One writer lane per row.
    const int mr = (r & 3) + 8 * (r >> 2) + 4 * h;
    if (m == mr) {
      const unsigned int kb = __float_as_uint(kv);
      tok_s[hw][tg * 32 + mr] = hw * 4096 + (int)(kb & 0xFFu) * 32 + mo;
      mind_s[hw][tg * 32 + mr] =
          __uint_as_float(kb & 0xFFFFFF00u) - 64.0f + znorm;
    }
  }
  __syncthreads();

  float* counts = ws + WS_COUNTS;
  float* embsum = ws + WS_EMBSUM;

  // merge code-halves (strict '<' keeps half0 on ties), qe partial + counts
  if (tid < 128) {
    const float d0 = mind_s[0][tid], d1 = mind_s[1][tid];
    const int   i0 = tok_s[0][tid],  i1 = tok_s[1][tid];
    const bool t1 = d1 < d0;
    const float dm = t1 ? d1 : d0;
    const int   im = t1 ? i1 : i0;
    tok_s[0][tid] = im;
    float qe = dm;
#pragma unroll
    for (int mm = 32; mm >= 1; mm >>= 1) qe += __shfl_xor(qe, mm);
    if ((tid & 63) == 0) atomicAdd(ws + WS_QE, qe);
    atomicAdd(&counts[im], 1.0f);
  }
  __syncthreads();

  // segment-sum of z: wave-coalesced atomics (64 consecutive floats/instr)
#pragma unroll 4
  for (int t = 0; t < 16; ++t) {
    const int row = w * 16 + t;
    const int tk = tok_s[0][row];
    const float zv = z[(size_t)(tb + row) * D_DIM + lane];
    atomicAdd(&embsum[(size_t)tk * D_DIM + lane], zv);
  }
}

// ---------------------------------------------------------------------------
// Fused finalize: n = 0.9*sum(cs) + 0.1*N_TOK is precomputed by vq_prep
// (sum(counts) == N_TOK exactly), so ncs/nea/weight all finalize in one pass.
__global__ void vq_finalize(const float* __restrict__ cluster_size,
                            const float* __restrict__ embed_avg,
                            const float* __restrict__ ws, float* __restrict__ out)
{
  const int idx = blockIdx.x * 256 + threadIdx.x;   // over K*D
  const int k = idx >> 6;
  const float ncs = cluster_size[k] * DECAY + OMD * ws[WS_COUNTS + k];
  const float nea = embed_avg[idx] * DECAY + OMD * ws[WS_EMBSUM + idx];
  out[OUT_EA + idx] = nea;
  float n = OMD * (float)N_TOK;
#pragma unroll
  for (int i = 0; i < 8; ++i) n += ws[WS_NSUM + (i << 5)];
  const float sm = (ncs + EPS) / (n + K_CODE * EPS) * n;
  out[OUT_W + idx] = nea / sm;
  if ((idx & 63) == 0) out[OUT_CS + k] = ncs;
  if (idx == 0) out[OUT_QE] = ws[WS_QE] * (1.0f / N_TOK);
}

// ---------------------------------------------------------------------------
extern "C" void kernel_launch(void* const* d_in, const int* in_sizes, int n_in,
                              void* d_out, int out_size, void* d_ws, size_t ws_size,
                              hipStream_t stream) {
  const float* z  = (const float*)d_in[0];
  const float* w  = (const float*)d_in[1];
  const float* cs = (const float*)d_in[2];
  const float* ea = (const float*)d_in[3];
  float* out = (float*)d_out;
  float* ws  = (float*)d_ws;

  (void)hipMemsetAsync(d_ws, 0, (size_t)WS_ZERO * sizeof(float), stream);

  vq_prep<<<K_CODE / 4, 256, 0, stream>>>(w, cs, ws);
  vq_argmin<<<N_TOK / 128, 512, 0, stream>>>(z, ws);
  vq_finalize<<<K_CODE * D_DIM / 256, 256, 0, stream>>>(cs, ea, ws, out);
}